// Round 16
// baseline (2303.197 us; speedup 1.0000x reference)
//
#include <hip/hip_runtime.h>
#include <math.h>

#define T_STEPS 1024
#define BATCH   512
#define DZ      256
#define DH      256
#define RANK    8
#define DY      16

// ===== Main kernel: 256 blocks x 512 threads, 2 batch elements/block. =====
// PAIR-SPLIT: thread (i = tid>>1, p = tid&1) owns the HALF-row
// W_zz[i,128p..+128) (64 h2) + Wz_in[i,32p..+32) (16 h2) + W_in[i,16p..+16)
// (8 h2) = 88 weight regs, computes half-dots for BOTH batches (176 dot2,
// work conserved), combines halves with one shfl_xor(.,1) per quantity.
// Keeps peak live ~130 regs -> no AGPR stash -> no v_accvgpr_read tax in
// the hot loop (R14: 184 persistent h2 in a 128-VGPR budget put ~56 h2 in
// AGPRs; VALUBusy 51% at ~2x the dot2 estimate).
//
// R15 BUG FIXED HERE: consumption loops must match half-row sizes —
// Wz_in loop m<4 (4 uint4 = 32 f16, wzi[0..15]) and W_in consumes 2 uint4
// (16 f16, wi[0..7]). R15 ran m<2 / 1 uint4 -> dropped products -> 0.657.
//
// 2-barrier step (R12/R14-validated, absmax 0.0039):
//   A: {prefetch, rank-group gl via projected Pz/Pzi, half-dots both
//       batches, pair-combine via shfl}                 -> barrier B
//   B: {batch-p z/h updates, double-buffered publish}   -> barrier A
// out-GEMV in a separate memory-bound post-kernel (reads states_h).

typedef _Float16 f16;
typedef _Float16 h2 __attribute__((ext_vector_type(2)));

__device__ __forceinline__ h2 pack2(float a, float b) {
    h2 r; r.x = (f16)a; r.y = (f16)b; return r;
}
__device__ __forceinline__ h2 bc(unsigned u) { return __builtin_bit_cast(h2, u); }

__device__ __forceinline__ float dot2(h2 a, h2 b, float c) {
#if __has_builtin(__builtin_amdgcn_fdot2)
    return __builtin_amdgcn_fdot2(a, b, c, false);
#else
    return fmaf((float)a.x, (float)b.x, fmaf((float)a.y, (float)b.y, c));
#endif
}

__device__ __forceinline__ float fast_tanh(float x) {
    const float e = __expf(2.0f * x);
    return 1.0f - 2.0f / (e + 1.0f);
}

__global__ __launch_bounds__(512, 1)
void nmrnn_main(
    const float* __restrict__ s, const float* __restrict__ c,
    const float* __restrict__ W_zz, const float* __restrict__ Wz_in,
    const float* __restrict__ bz_in, const float* __restrict__ Wz_out,
    const float* __restrict__ bz_out, const float* __restrict__ U,
    const float* __restrict__ V, const float* __restrict__ W_in,
    const float* __restrict__ b_in,
    float* __restrict__ states)
{
    __shared__ __align__(16) f16 tzh[2][2][DZ];   // [buf][batch][k] tanh(z)
    __shared__ __align__(16) f16 thh[2][2][DH];   // tanh(h)
    __shared__ __align__(16) f16 sclh[2][2][64];  // [s|c]
    __shared__ __align__(16) f16 vt16[RANK][DH];  // V^T
    __shared__ __align__(16) f16 pz16[RANK][DZ];  // Wzo @ W_zz
    __shared__ __align__(16) f16 pzi16[RANK][64]; // Wzo @ Wz_in
    __shared__ float gl[2][RANK];                 // [batch][r]
    // ~14 KB

    const int tid = threadIdx.x;
    const int p   = tid & 1;         // K-half
    const int i   = tid >> 1;        // neuron 0..255
    const int l32 = tid & 31;
    const int b0  = blockIdx.x * 2;
    // rank group: 16 groups of 32 lanes -> (rb, rr)
    const int gg = tid >> 5;
    const int rr = gg & 7;
    const int rb = gg >> 3;

    // ---- half-row f16 weights in registers (88 VGPRs) ----
    h2 wzz[64];
    #pragma unroll
    for (int m = 0; m < 32; ++m) {
        const float4 v4 = *(const float4*)&W_zz[i * 256 + (p << 7) + (m << 2)];
        wzz[2 * m]     = pack2(v4.x, v4.y);
        wzz[2 * m + 1] = pack2(v4.z, v4.w);
    }
    h2 wzi[16];
    #pragma unroll
    for (int m = 0; m < 8; ++m) {
        const float4 v4 = *(const float4*)&Wz_in[i * 64 + (p << 5) + (m << 2)];
        wzi[2 * m]     = pack2(v4.x, v4.y);
        wzi[2 * m + 1] = pack2(v4.z, v4.w);
    }
    h2 wi[8];
    #pragma unroll
    for (int m = 0; m < 4; ++m) {
        const float4 v4 = *(const float4*)&W_in[i * 32 + (p << 4) + (m << 2)];
        wi[2 * m]     = pack2(v4.x, v4.y);
        wi[2 * m + 1] = pack2(v4.z, v4.w);
    }
    float uu[8];
    {
        const float4 a  = *(const float4*)&U[i * 8];
        const float4 b4 = *(const float4*)&U[i * 8 + 4];
        uu[0]=a.x; uu[1]=a.y; uu[2]=a.z; uu[3]=a.w;
        uu[4]=b4.x; uu[5]=b4.y; uu[6]=b4.z; uu[7]=b4.w;
    }

    // ---- one-time staging ----
    if (tid < 256) {
        #pragma unroll
        for (int r = 0; r < RANK; ++r) vt16[r][tid] = (f16)V[tid * RANK + r];
    }
    // Pz = Wzo @ W_zz  (8x256, 4 entries/thread)
    #pragma unroll
    for (int pp = 0; pp < 4; ++pp) {
        const int e = pp * 512 + tid;
        const int r = e >> 8, col = e & 255;
        const float* wrow = &Wz_out[r * 256];
        float a0 = 0.f, a1 = 0.f;
        #pragma unroll 4
        for (int k = 0; k < 256; k += 2) {
            a0 = fmaf(wrow[k],     W_zz[k * 256 + col],       a0);
            a1 = fmaf(wrow[k + 1], W_zz[(k + 1) * 256 + col], a1);
        }
        pz16[r][col] = (f16)(a0 + a1);
    }
    {   // Pzi = Wzo @ Wz_in (8x64, 1 entry/thread)
        const int r = tid >> 6, j = tid & 63;
        const float* wrow = &Wz_out[r * 256];
        float a0 = 0.f, a1 = 0.f;
        #pragma unroll 4
        for (int k = 0; k < 256; k += 2) {
            a0 = fmaf(wrow[k],     Wz_in[k * 64 + j],       a0);
            a1 = fmaf(wrow[k + 1], Wz_in[(k + 1) * 64 + j], a1);
        }
        pzi16[r][j] = (f16)(a0 + a1);
    }
    tzh[0][p][i] = (f16)0.f;   // (i,p) covers [2][256] exactly
    thh[0][p][i] = (f16)0.f;
    if (tid < 128) {  // t=0 inputs
        const int b2 = tid >> 6, rI = tid & 63;
        const size_t base = (size_t)(b0 + b2) * 32;
        sclh[0][b2][rI] = (f16)((rI < 32) ? s[base + rI] : c[base + rI - 32]);
    }

    const float bz = bz_in[i];
    const float bh = b_in[i];
    float z_r = 0.f, h_r = 0.f;   // state of batch p, neuron i

    // rank-group persistent: czb (const), rzb (recurrent)
    float czb, rzb;
    {
        float cz = 0.f;
        #pragma unroll
        for (int m = 0; m < 8; ++m) {
            const int k = l32 + 32 * m;
            cz = fmaf(bz_in[k], Wz_out[rr * 256 + k], cz);
        }
        #pragma unroll
        for (int off = 16; off >= 1; off >>= 1) cz += __shfl_xor(cz, off);
        const float bzo_r = bz_out[rr];
        czb = cz + bzo_r;
        rzb = bzo_r;
    }

    int cur = 0;
    __syncthreads();   // staging done

    for (int t = 0; t < T_STEPS; ++t) {
        // ================= PHASE A =================
        float pfn = 0.f;
        if (tid < 128 && t + 1 < T_STEPS) {
            const int b2 = tid >> 6, rI = tid & 63;
            const size_t base = ((size_t)(t + 1) * BATCH + b0 + b2) * 32;
            pfn = (rI < 32) ? s[base + rI] : c[base + rI - 32];
        }

        // rank duty (all 16 groups): hp, zp -> rzb -> gl[rb][rr]
        {
            const h2* tp  = (const h2*)&thh[cur][rb][0];
            const h2* vp  = (const h2*)&vt16[rr][0];
            const h2* tzp = (const h2*)&tzh[cur][rb][0];
            const h2* pzp = (const h2*)&pz16[rr][0];
            float hp0 = 0.f, hp1 = 0.f, zp0 = 0.f, zp1 = 0.f;
            hp0 = dot2(tp[l32],       vp[l32],       hp0);
            hp1 = dot2(tp[l32 + 32],  vp[l32 + 32],  hp1);
            hp0 = dot2(tp[l32 + 64],  vp[l32 + 64],  hp0);
            hp1 = dot2(tp[l32 + 96],  vp[l32 + 96],  hp1);
            zp0 = dot2(tzp[l32],      pzp[l32],      zp0);
            zp1 = dot2(tzp[l32 + 32], pzp[l32 + 32], zp1);
            zp0 = dot2(tzp[l32 + 64], pzp[l32 + 64], zp0);
            zp1 = dot2(tzp[l32 + 96], pzp[l32 + 96], zp1);
            const h2* scp  = (const h2*)&sclh[cur][rb][0];
            const h2* pzip = (const h2*)&pzi16[rr][0];
            zp0 = dot2(scp[l32], pzip[l32], zp0);
            float hp = hp0 + hp1, zp = zp0 + zp1;
            #pragma unroll
            for (int off = 16; off >= 1; off >>= 1) {
                hp += __shfl_xor(hp, off);
                zp += __shfl_xor(zp, off);
            }
            rzb = 0.99f * rzb + 0.01f * (zp + czb);
            const float sg = 1.0f / (1.0f + __expf(-rzb));
            if (l32 == 0) gl[rb][rr] = sg * hp;
        }

        // half-row dots for BOTH batches (2 chains each)
        float a00 = 0.f, a01 = 0.f, a10 = 0.f, a11 = 0.f;
        float wh0 = 0.f, wh1 = 0.f;
        {
            const uint4* tz0 = (const uint4*)&tzh[cur][0][p << 7];
            const uint4* tz1 = (const uint4*)&tzh[cur][1][p << 7];
            #pragma unroll
            for (int m = 0; m < 16; ++m) {  // 16 uint4 = 128 f16 = half row
                const uint4 u0 = tz0[m];
                const uint4 u1 = tz1[m];
                a00 = dot2(wzz[4 * m + 0], bc(u0.x), a00);
                a01 = dot2(wzz[4 * m + 1], bc(u0.y), a01);
                a00 = dot2(wzz[4 * m + 2], bc(u0.z), a00);
                a01 = dot2(wzz[4 * m + 3], bc(u0.w), a01);
                a10 = dot2(wzz[4 * m + 0], bc(u1.x), a10);
                a11 = dot2(wzz[4 * m + 1], bc(u1.y), a11);
                a10 = dot2(wzz[4 * m + 2], bc(u1.z), a10);
                a11 = dot2(wzz[4 * m + 3], bc(u1.w), a11);
            }
            // Wz_in half-row: 4 uint4 = 32 f16, wzi[0..15]  (R15 bug: was m<2)
            const uint4* sp0 = (const uint4*)&sclh[cur][0][p << 5];
            const uint4* sp1 = (const uint4*)&sclh[cur][1][p << 5];
            #pragma unroll
            for (int m = 0; m < 4; ++m) {
                const uint4 u0 = sp0[m];
                const uint4 u1 = sp1[m];
                a00 = dot2(wzi[4 * m + 0], bc(u0.x), a00);
                a01 = dot2(wzi[4 * m + 1], bc(u0.y), a01);
                a00 = dot2(wzi[4 * m + 2], bc(u0.z), a00);
                a01 = dot2(wzi[4 * m + 3], bc(u0.w), a01);
                a10 = dot2(wzi[4 * m + 0], bc(u1.x), a10);
                a11 = dot2(wzi[4 * m + 1], bc(u1.y), a11);
                a10 = dot2(wzi[4 * m + 2], bc(u1.z), a10);
                a11 = dot2(wzi[4 * m + 3], bc(u1.w), a11);
            }
            // W_in half-row: 2 uint4 = 16 f16, wi[0..7]  (R15 bug: was 1 uint4)
            const uint4* w0p = (const uint4*)&sclh[cur][0][p << 4];
            const uint4* w1p = (const uint4*)&sclh[cur][1][p << 4];
            #pragma unroll
            for (int m = 0; m < 2; ++m) {
                const uint4 u0 = w0p[m];
                const uint4 u1 = w1p[m];
                wh0 = dot2(wi[4 * m + 0], bc(u0.x), wh0);
                wh0 = dot2(wi[4 * m + 1], bc(u0.y), wh0);
                wh0 = dot2(wi[4 * m + 2], bc(u0.z), wh0);
                wh0 = dot2(wi[4 * m + 3], bc(u0.w), wh0);
                wh1 = dot2(wi[4 * m + 0], bc(u1.x), wh1);
                wh1 = dot2(wi[4 * m + 1], bc(u1.y), wh1);
                wh1 = dot2(wi[4 * m + 2], bc(u1.z), wh1);
                wh1 = dot2(wi[4 * m + 3], bc(u1.w), wh1);
            }
        }
        // pair-combine: lanes (2k, 2k+1) hold the two K-halves of neuron i
        float z0 = a00 + a01;
        float z1 = a10 + a11;
        z0  += __shfl_xor(z0, 1);
        z1  += __shfl_xor(z1, 1);
        wh0 += __shfl_xor(wh0, 1);
        wh1 += __shfl_xor(wh1, 1);
        __syncthreads();  // B

        // ================= PHASE B ================= (thread handles batch p)
        const float zsum = (p == 0 ? z0 : z1) + bz;
        z_r = 0.99f * z_r + 0.01f * zsum;
        tzh[cur ^ 1][p][i] = (f16)fast_tanh(z_r);
        states[((size_t)t * BATCH + b0 + p) * 512 + i] = z_r;

        const float4 g0 = *(const float4*)&gl[p][0];
        const float4 g1 = *(const float4*)&gl[p][4];
        float hs0 = (p == 0 ? wh0 : wh1) + bh, hs1 = 0.f;
        hs0 = fmaf(uu[0], g0.x, hs0); hs1 = fmaf(uu[1], g0.y, hs1);
        hs0 = fmaf(uu[2], g0.z, hs0); hs1 = fmaf(uu[3], g0.w, hs1);
        hs0 = fmaf(uu[4], g1.x, hs0); hs1 = fmaf(uu[5], g1.y, hs1);
        hs0 = fmaf(uu[6], g1.z, hs0); hs1 = fmaf(uu[7], g1.w, hs1);
        h_r = 0.9f * h_r + 0.1f * (hs0 + hs1);
        thh[cur ^ 1][p][i] = (f16)fast_tanh(h_r);
        states[((size_t)t * BATCH + b0 + p) * 512 + 256 + i] = h_r;

        if (tid < 128 && t + 1 < T_STEPS)
            sclh[cur ^ 1][tid >> 6][tid & 63] = (f16)pfn;
        cur ^= 1;
        __syncthreads();  // A
    }
}

// ===== Post-kernel: out[t,b,:] = tanh(states_h[t,b,:]) @ W_out^T + b_out =====
__global__ __launch_bounds__(256)
void nmrnn_out(const float* __restrict__ states,
               const float* __restrict__ W_out,
               const float* __restrict__ b_out,
               float* __restrict__ out)
{
    __shared__ __align__(16) f16 th[16][264];   // +8 pad
    __shared__ __align__(16) f16 wo[16][258];   // +2 pad
    __shared__ float bo[DY];

    const int tid = threadIdx.x;
    #pragma unroll
    for (int it = 0; it < 16; ++it) {
        const int e = it * 256 + tid;
        wo[e >> 8][e & 255] = (f16)W_out[e];
    }
    if (tid < DY) bo[tid] = b_out[tid];

    const size_t row0 = (size_t)blockIdx.x * 16;
    #pragma unroll
    for (int it = 0; it < 16; ++it) {
        const float v = states[(row0 + it) * 512 + 256 + tid];
        th[it][tid] = (f16)fast_tanh(v);
    }
    __syncthreads();

    const int r = tid >> 4, y = tid & 15;
    const h2* tp = (const h2*)&th[r][0];
    const h2* wp = (const h2*)&wo[y][0];
    float a0 = 0.f, a1 = 0.f, a2 = 0.f, a3 = 0.f;
    #pragma unroll
    for (int pp = 0; pp < 128; pp += 4) {
        a0 = dot2(tp[pp],     wp[pp],     a0);
        a1 = dot2(tp[pp + 1], wp[pp + 1], a1);
        a2 = dot2(tp[pp + 2], wp[pp + 2], a2);
        a3 = dot2(tp[pp + 3], wp[pp + 3], a3);
    }
    out[row0 * 16 + tid] = (a0 + a1) + (a2 + a3) + bo[y];
}

extern "C" void kernel_launch(void* const* d_in, const int* in_sizes, int n_in,
                              void* d_out, int out_size, void* d_ws, size_t ws_size,
                              hipStream_t stream) {
    const float* s     = (const float*)d_in[0];
    const float* c     = (const float*)d_in[1];
    const float* W_zz  = (const float*)d_in[2];
    const float* Wz_in = (const float*)d_in[3];
    const float* bz_in = (const float*)d_in[4];
    const float* Wz_out= (const float*)d_in[5];
    const float* bz_out= (const float*)d_in[6];
    const float* U     = (const float*)d_in[7];
    const float* V     = (const float*)d_in[8];
    const float* W_in  = (const float*)d_in[9];
    const float* b_in  = (const float*)d_in[10];
    const float* W_out = (const float*)d_in[11];
    const float* b_out = (const float*)d_in[12];

    float* out    = (float*)d_out;
    float* states = out + (size_t)T_STEPS * BATCH * DY;

    hipLaunchKernelGGL(nmrnn_main, dim3(BATCH / 2), dim3(512), 0, stream,
                       s, c, W_zz, Wz_in, bz_in, Wz_out, bz_out, U, V,
                       W_in, b_in, states);

    hipLaunchKernelGGL(nmrnn_out, dim3(T_STEPS * BATCH / 16), dim3(256), 0,
                       stream, states, W_out, b_out, out);
}

// Round 17
// 2093.822 us; speedup vs baseline: 1.1000x; 1.1000x over previous
//
#include <hip/hip_runtime.h>
#include <math.h>

#define T_STEPS 1024
#define BATCH   512
#define DZ      256
#define DH      256
#define RANK    8
#define DY      16

// ===== Main kernel: 256 blocks x 512 threads, 2 batch elements/block. =====
// PAIR-SPLIT (R16, validated): thread (i = tid>>1, p = tid&1) owns the
// HALF-row W_zz[i,128p..+128) (64 h2) + Wz_in (16) + W_in (8) = 88 weight
// regs, computes half-dots for BOTH batches, combines with shfl_xor(.,1).
//
// R17 FIX — BANK-SKEWED LDS LAYOUTS. R16 put p in the lane LSB, so each
// main-loop read hit two addresses 256B apart (same banks -> 2-way
// serialize) and each phase-B f16 write hit two batch regions 512B apart
// (same 16 banks): SQ_LDS_BANK_CONFLICT = 2.77e8 (~19% of cycles). Here:
//   tz:  idx = buf*576 + batch*288 + khalf*136 + pos   (f16 units)
//        khalf stride 272B -> +4 banks  (disjoint from 4-bank b128 read)
//        batch stride 576B -> +16 banks (even/odd write footprints disjoint)
//   th:  idx = buf*576 + batch*288 + pos
//   vt16/pz16 rows padded to 288 f16 (rank-group 2-way read relief).
//
// 2-barrier step (R12/R16-validated, absmax 0.0039):
//   A: {prefetch, rank-group gl via projected Pz/Pzi, half-dots both
//       batches, pair-combine via shfl}                 -> barrier B
//   B: {batch-p z/h updates, double-buffered publish}   -> barrier A
// out-GEMV in a separate memory-bound post-kernel (reads states_h).

typedef _Float16 f16;
typedef _Float16 h2 __attribute__((ext_vector_type(2)));

__device__ __forceinline__ h2 pack2(float a, float b) {
    h2 r; r.x = (f16)a; r.y = (f16)b; return r;
}
__device__ __forceinline__ h2 bc(unsigned u) { return __builtin_bit_cast(h2, u); }

__device__ __forceinline__ float dot2(h2 a, h2 b, float c) {
#if __has_builtin(__builtin_amdgcn_fdot2)
    return __builtin_amdgcn_fdot2(a, b, c, false);
#else
    return fmaf((float)a.x, (float)b.x, fmaf((float)a.y, (float)b.y, c));
#endif
}

__device__ __forceinline__ float fast_tanh(float x) {
    const float e = __expf(2.0f * x);
    return 1.0f - 2.0f / (e + 1.0f);
}

// skewed tz index (f16 units): buf in {0,1}, b in {0,1}, kh in {0,1}, pos<136
#define TZI(buf, b, kh) ((buf) * 576 + (b) * 288 + (kh) * 136)
#define THI(buf, b)     ((buf) * 576 + (b) * 288)

__global__ __launch_bounds__(512, 1)
void nmrnn_main(
    const float* __restrict__ s, const float* __restrict__ c,
    const float* __restrict__ W_zz, const float* __restrict__ Wz_in,
    const float* __restrict__ bz_in, const float* __restrict__ Wz_out,
    const float* __restrict__ bz_out, const float* __restrict__ U,
    const float* __restrict__ V, const float* __restrict__ W_in,
    const float* __restrict__ b_in,
    float* __restrict__ states)
{
    __shared__ __align__(16) f16 tzbuf[2 * 576];  // skewed tanh(z), dbuf
    __shared__ __align__(16) f16 thbuf[2 * 576];  // skewed tanh(h), dbuf
    __shared__ __align__(16) f16 sclh[2][2][64];  // [buf][batch][s|c]
    __shared__ __align__(16) f16 vt16[RANK][288]; // V^T, padded row
    __shared__ __align__(16) f16 pz16[RANK][288]; // Wzo @ W_zz, padded row
    __shared__ __align__(16) f16 pzi16[RANK][64]; // Wzo @ Wz_in
    __shared__ float gl[2][RANK];                 // [batch][r]
    // ~15 KB

    const int tid = threadIdx.x;
    const int p   = tid & 1;         // K-half
    const int i   = tid >> 1;        // neuron 0..255
    const int l32 = tid & 31;
    const int b0  = blockIdx.x * 2;
    // rank group: 16 groups of 32 lanes -> (rb, rr)
    const int gg = tid >> 5;
    const int rr = gg & 7;
    const int rb = gg >> 3;

    // ---- half-row f16 weights in registers (88 VGPRs) ----
    h2 wzz[64];
    #pragma unroll
    for (int m = 0; m < 32; ++m) {
        const float4 v4 = *(const float4*)&W_zz[i * 256 + (p << 7) + (m << 2)];
        wzz[2 * m]     = pack2(v4.x, v4.y);
        wzz[2 * m + 1] = pack2(v4.z, v4.w);
    }
    h2 wzi[16];
    #pragma unroll
    for (int m = 0; m < 8; ++m) {
        const float4 v4 = *(const float4*)&Wz_in[i * 64 + (p << 5) + (m << 2)];
        wzi[2 * m]     = pack2(v4.x, v4.y);
        wzi[2 * m + 1] = pack2(v4.z, v4.w);
    }
    h2 wi[8];
    #pragma unroll
    for (int m = 0; m < 4; ++m) {
        const float4 v4 = *(const float4*)&W_in[i * 32 + (p << 4) + (m << 2)];
        wi[2 * m]     = pack2(v4.x, v4.y);
        wi[2 * m + 1] = pack2(v4.z, v4.w);
    }
    float uu[8];
    {
        const float4 a  = *(const float4*)&U[i * 8];
        const float4 b4 = *(const float4*)&U[i * 8 + 4];
        uu[0]=a.x; uu[1]=a.y; uu[2]=a.z; uu[3]=a.w;
        uu[4]=b4.x; uu[5]=b4.y; uu[6]=b4.z; uu[7]=b4.w;
    }

    // ---- one-time staging ----
    if (tid < 256) {
        #pragma unroll
        for (int r = 0; r < RANK; ++r) vt16[r][tid] = (f16)V[tid * RANK + r];
    }
    // Pz = Wzo @ W_zz  (8x256, 4 entries/thread)
    #pragma unroll
    for (int pp = 0; pp < 4; ++pp) {
        const int e = pp * 512 + tid;
        const int r = e >> 8, col = e & 255;
        const float* wrow = &Wz_out[r * 256];
        float a0 = 0.f, a1 = 0.f;
        #pragma unroll 4
        for (int k = 0; k < 256; k += 2) {
            a0 = fmaf(wrow[k],     W_zz[k * 256 + col],       a0);
            a1 = fmaf(wrow[k + 1], W_zz[(k + 1) * 256 + col], a1);
        }
        pz16[r][col] = (f16)(a0 + a1);
    }
    {   // Pzi = Wzo @ Wz_in (8x64, 1 entry/thread)
        const int r = tid >> 6, j = tid & 63;
        const float* wrow = &Wz_out[r * 256];
        float a0 = 0.f, a1 = 0.f;
        #pragma unroll 4
        for (int k = 0; k < 256; k += 2) {
            a0 = fmaf(wrow[k],     Wz_in[k * 64 + j],       a0);
            a1 = fmaf(wrow[k + 1], Wz_in[(k + 1) * 64 + j], a1);
        }
        pzi16[r][j] = (f16)(a0 + a1);
    }
    // init z0 = h0 = 0: (i,p) covers [2][256] exactly
    tzbuf[TZI(0, p, i >> 7) + (i & 127)] = (f16)0.f;
    thbuf[THI(0, p) + i] = (f16)0.f;
    if (tid < 128) {  // t=0 inputs
        const int b2 = tid >> 6, rI = tid & 63;
        const size_t base = (size_t)(b0 + b2) * 32;
        sclh[0][b2][rI] = (f16)((rI < 32) ? s[base + rI] : c[base + rI - 32]);
    }

    const float bz = bz_in[i];
    const float bh = b_in[i];
    float z_r = 0.f, h_r = 0.f;   // state of batch p, neuron i

    // rank-group persistent: czb (const), rzb (recurrent)
    float czb, rzb;
    {
        float cz = 0.f;
        #pragma unroll
        for (int m = 0; m < 8; ++m) {
            const int k = l32 + 32 * m;
            cz = fmaf(bz_in[k], Wz_out[rr * 256 + k], cz);
        }
        #pragma unroll
        for (int off = 16; off >= 1; off >>= 1) cz += __shfl_xor(cz, off);
        const float bzo_r = bz_out[rr];
        czb = cz + bzo_r;
        rzb = bzo_r;
    }

    int cur = 0;
    __syncthreads();   // staging done

    for (int t = 0; t < T_STEPS; ++t) {
        // ================= PHASE A =================
        float pfn = 0.f;
        if (tid < 128 && t + 1 < T_STEPS) {
            const int b2 = tid >> 6, rI = tid & 63;
            const size_t base = ((size_t)(t + 1) * BATCH + b0 + b2) * 32;
            pfn = (rI < 32) ? s[base + rI] : c[base + rI - 32];
        }

        // rank duty (all 16 groups): hp, zp -> rzb -> gl[rb][rr]
        {
            const h2* tp   = (const h2*)&thbuf[THI(cur, rb)];
            const h2* vp   = (const h2*)&vt16[rr][0];
            const h2* tzlo = (const h2*)&tzbuf[TZI(cur, rb, 0)];
            const h2* tzhi = (const h2*)&tzbuf[TZI(cur, rb, 1)];
            const h2* pzlo = (const h2*)&pz16[rr][0];
            const h2* pzhi = (const h2*)&pz16[rr][128 * 2];  // f16 idx 256? no:
            // pz16 row is f16[288]; h2 view: row h2 index 0..143. khalf hi
            // starts at f16 128*? -- pz is UNSPLIT (plain 256 f16): hi half
            // begins at h2 index 64.
            pzhi = (const h2*)&pz16[rr][128];
            float hp0 = 0.f, hp1 = 0.f, zp0 = 0.f, zp1 = 0.f;
            hp0 = dot2(tp[l32],       vp[l32],       hp0);
            hp1 = dot2(tp[l32 + 32],  vp[l32 + 32],  hp1);
            hp0 = dot2(tp[l32 + 64],  vp[l32 + 64],  hp0);
            hp1 = dot2(tp[l32 + 96],  vp[l32 + 96],  hp1);
            zp0 = dot2(tzlo[l32],      pzlo[l32],      zp0);
            zp1 = dot2(tzlo[l32 + 32], pzlo[l32 + 32], zp1);
            zp0 = dot2(tzhi[l32],      pzhi[l32],      zp0);
            zp1 = dot2(tzhi[l32 + 32], pzhi[l32 + 32], zp1);
            const h2* scp  = (const h2*)&sclh[cur][rb][0];
            const h2* pzip = (const h2*)&pzi16[rr][0];
            zp0 = dot2(scp[l32], pzip[l32], zp0);
            float hp = hp0 + hp1, zp = zp0 + zp1;
            #pragma unroll
            for (int off = 16; off >= 1; off >>= 1) {
                hp += __shfl_xor(hp, off);
                zp += __shfl_xor(zp, off);
            }
            rzb = 0.99f * rzb + 0.01f * (zp + czb);
            const float sg = 1.0f / (1.0f + __expf(-rzb));
            if (l32 == 0) gl[rb][rr] = sg * hp;
        }

        // half-row dots for BOTH batches (2 chains each)
        float a00 = 0.f, a01 = 0.f, a10 = 0.f, a11 = 0.f;
        float wh0 = 0.f, wh1 = 0.f;
        {
            const uint4* tz0 = (const uint4*)&tzbuf[TZI(cur, 0, p)];
            const uint4* tz1 = (const uint4*)&tzbuf[TZI(cur, 1, p)];
            #pragma unroll
            for (int m = 0; m < 16; ++m) {  // 16 uint4 = 128 f16 = half row
                const uint4 u0 = tz0[m];
                const uint4 u1 = tz1[m];
                a00 = dot2(wzz[4 * m + 0], bc(u0.x), a00);
                a01 = dot2(wzz[4 * m + 1], bc(u0.y), a01);
                a00 = dot2(wzz[4 * m + 2], bc(u0.z), a00);
                a01 = dot2(wzz[4 * m + 3], bc(u0.w), a01);
                a10 = dot2(wzz[4 * m + 0], bc(u1.x), a10);
                a11 = dot2(wzz[4 * m + 1], bc(u1.y), a11);
                a10 = dot2(wzz[4 * m + 2], bc(u1.z), a10);
                a11 = dot2(wzz[4 * m + 3], bc(u1.w), a11);
            }
            // Wz_in half-row: 4 uint4 = 32 f16, wzi[0..15]
            const uint4* sp0 = (const uint4*)&sclh[cur][0][p << 5];
            const uint4* sp1 = (const uint4*)&sclh[cur][1][p << 5];
            #pragma unroll
            for (int m = 0; m < 4; ++m) {
                const uint4 u0 = sp0[m];
                const uint4 u1 = sp1[m];
                a00 = dot2(wzi[4 * m + 0], bc(u0.x), a00);
                a01 = dot2(wzi[4 * m + 1], bc(u0.y), a01);
                a00 = dot2(wzi[4 * m + 2], bc(u0.z), a00);
                a01 = dot2(wzi[4 * m + 3], bc(u0.w), a01);
                a10 = dot2(wzi[4 * m + 0], bc(u1.x), a10);
                a11 = dot2(wzi[4 * m + 1], bc(u1.y), a11);
                a10 = dot2(wzi[4 * m + 2], bc(u1.z), a10);
                a11 = dot2(wzi[4 * m + 3], bc(u1.w), a11);
            }
            // W_in half-row: 2 uint4 = 16 f16, wi[0..7]
            const uint4* w0p = (const uint4*)&sclh[cur][0][p << 4];
            const uint4* w1p = (const uint4*)&sclh[cur][1][p << 4];
            #pragma unroll
            for (int m = 0; m < 2; ++m) {
                const uint4 u0 = w0p[m];
                const uint4 u1 = w1p[m];
                wh0 = dot2(wi[4 * m + 0], bc(u0.x), wh0);
                wh0 = dot2(wi[4 * m + 1], bc(u0.y), wh0);
                wh0 = dot2(wi[4 * m + 2], bc(u0.z), wh0);
                wh0 = dot2(wi[4 * m + 3], bc(u0.w), wh0);
                wh1 = dot2(wi[4 * m + 0], bc(u1.x), wh1);
                wh1 = dot2(wi[4 * m + 1], bc(u1.y), wh1);
                wh1 = dot2(wi[4 * m + 2], bc(u1.z), wh1);
                wh1 = dot2(wi[4 * m + 3], bc(u1.w), wh1);
            }
        }
        // pair-combine: lanes (2k, 2k+1) hold the two K-halves of neuron i
        float z0 = a00 + a01;
        float z1 = a10 + a11;
        z0  += __shfl_xor(z0, 1);
        z1  += __shfl_xor(z1, 1);
        wh0 += __shfl_xor(wh0, 1);
        wh1 += __shfl_xor(wh1, 1);
        __syncthreads();  // B

        // ================= PHASE B ================= (thread handles batch p)
        const float zsum = (p == 0 ? z0 : z1) + bz;
        z_r = 0.99f * z_r + 0.01f * zsum;
        tzbuf[TZI(cur ^ 1, p, i >> 7) + (i & 127)] = (f16)fast_tanh(z_r);
        states[((size_t)t * BATCH + b0 + p) * 512 + i] = z_r;

        const float4 g0 = *(const float4*)&gl[p][0];
        const float4 g1 = *(const float4*)&gl[p][4];
        float hs0 = (p == 0 ? wh0 : wh1) + bh, hs1 = 0.f;
        hs0 = fmaf(uu[0], g0.x, hs0); hs1 = fmaf(uu[1], g0.y, hs1);
        hs0 = fmaf(uu[2], g0.z, hs0); hs1 = fmaf(uu[3], g0.w, hs1);
        hs0 = fmaf(uu[4], g1.x, hs0); hs1 = fmaf(uu[5], g1.y, hs1);
        hs0 = fmaf(uu[6], g1.z, hs0); hs1 = fmaf(uu[7], g1.w, hs1);
        h_r = 0.9f * h_r + 0.1f * (hs0 + hs1);
        thbuf[THI(cur ^ 1, p) + i] = (f16)fast_tanh(h_r);
        states[((size_t)t * BATCH + b0 + p) * 512 + 256 + i] = h_r;

        if (tid < 128 && t + 1 < T_STEPS)
            sclh[cur ^ 1][tid >> 6][tid & 63] = (f16)pfn;
        cur ^= 1;
        __syncthreads();  // A
    }
}

// ===== Post-kernel: out[t,b,:] = tanh(states_h[t,b,:]) @ W_out^T + b_out =====
__global__ __launch_bounds__(256)
void nmrnn_out(const float* __restrict__ states,
               const float* __restrict__ W_out,
               const float* __restrict__ b_out,
               float* __restrict__ out)
{
    __shared__ __align__(16) f16 th[16][264];   // +8 pad
    __shared__ __align__(16) f16 wo[16][258];   // +2 pad
    __shared__ float bo[DY];

    const int tid = threadIdx.x;
    #pragma unroll
    for (int it = 0; it < 16; ++it) {
        const int e = it * 256 + tid;
        wo[e >> 8][e & 255] = (f16)W_out[e];
    }
    if (tid < DY) bo[tid] = b_out[tid];

    const size_t row0 = (size_t)blockIdx.x * 16;
    #pragma unroll
    for (int it = 0; it < 16; ++it) {
        const float v = states[(row0 + it) * 512 + 256 + tid];
        th[it][tid] = (f16)fast_tanh(v);
    }
    __syncthreads();

    const int r = tid >> 4, y = tid & 15;
    const h2* tp = (const h2*)&th[r][0];
    const h2* wp = (const h2*)&wo[y][0];
    float a0 = 0.f, a1 = 0.f, a2 = 0.f, a3 = 0.f;
    #pragma unroll
    for (int pp = 0; pp < 128; pp += 4) {
        a0 = dot2(tp[pp],     wp[pp],     a0);
        a1 = dot2(tp[pp + 1], wp[pp + 1], a1);
        a2 = dot2(tp[pp + 2], wp[pp + 2], a2);
        a3 = dot2(tp[pp + 3], wp[pp + 3], a3);
    }
    out[row0 * 16 + tid] = (a0 + a1) + (a2 + a3) + bo[y];
}

extern "C" void kernel_launch(void* const* d_in, const int* in_sizes, int n_in,
                              void* d_out, int out_size, void* d_ws, size_t ws_size,
                              hipStream_t stream) {
    const float* s     = (const float*)d_in[0];
    const float* c     = (const float*)d_in[1];
    const float* W_zz  = (const float*)d_in[2];
    const float* Wz_in = (const float*)d_in[3];
    const float* bz_in = (const float*)d_in[4];
    const float* Wz_out= (const float*)d_in[5];
    const float* bz_out= (const float*)d_in[6];
    const float* U     = (const float*)d_in[7];
    const float* V     = (const float*)d_in[8];
    const float* W_in  = (const float*)d_in[9];
    const float* b_in  = (const float*)d_in[10];
    const float* W_out = (const float*)d_in[11];
    const float* b_out = (const float*)d_in[12];

    float* out    = (float*)d_out;
    float* states = out + (size_t)T_STEPS * BATCH * DY;

    hipLaunchKernelGGL(nmrnn_main, dim3(BATCH / 2), dim3(512), 0, stream,
                       s, c, W_zz, Wz_in, bz_in, Wz_out, bz_out, U, V,
                       W_in, b_in, states);

    hipLaunchKernelGGL(nmrnn_out, dim3(T_STEPS * BATCH / 16), dim3(256), 0,
                       stream, states, W_out, b_out, out);
}